// Round 1
// baseline (5567.238 us; speedup 1.0000x reference)
//
#include <hip/hip_runtime.h>
#include <cmath>

#define NTOK 1024
#define NH 8
#define DH 64
#define DIM 512
#define BATCH 4

__device__ __forceinline__ void fma4x4(float acc[4][4], const float4& av, const float4& bv) {
  const float a4[4] = {av.x, av.y, av.z, av.w};
  const float b4[4] = {bv.x, bv.y, bv.z, bv.w};
#pragma unroll
  for (int u = 0; u < 4; ++u)
#pragma unroll
    for (int v = 0; v < 4; ++v) acc[u][v] += a4[u] * b4[v];
}

// ---------------- Kernel 1: QKV GEMM ----------------
// (4096x512) @ (512x1536) -> q/k/v planes in (b,h,n,d) layout inside ws.
__global__ __launch_bounds__(256) void k_qkv(const float* __restrict__ x,
                                             const float* __restrict__ w,
                                             float* __restrict__ qkv) {
  __shared__ float As[32][68];   // [k][m] transposed
  __shared__ float Bs[32][68];   // [k][n]
  const int bx = blockIdx.x;     // 0..23 col tile (64 cols each)
  const int by = blockIdx.y;     // 0..63 row tile
  const int t = threadIdx.x;
  const int tx = t & 15, ty = t >> 4;
  const int m0 = by * 64, n0 = bx * 64;
  float acc[4][4] = {};
  for (int k0 = 0; k0 < 512; k0 += 32) {
#pragma unroll
    for (int l = 0; l < 2; ++l) {
      int idx = t + l * 256;
      {
        int row = idx >> 3, c4 = idx & 7;
        float4 a = *(const float4*)(x + (size_t)(m0 + row) * 512 + k0 + c4 * 4);
        As[c4 * 4 + 0][row] = a.x; As[c4 * 4 + 1][row] = a.y;
        As[c4 * 4 + 2][row] = a.z; As[c4 * 4 + 3][row] = a.w;
      }
      {
        int row = idx >> 4, c4 = idx & 15;
        *(float4*)(&Bs[row][c4 * 4]) =
            *(const float4*)(w + (size_t)(k0 + row) * 1536 + n0 + c4 * 4);
      }
    }
    __syncthreads();
#pragma unroll
    for (int kk = 0; kk < 32; ++kk) {
      float4 av = *(const float4*)(&As[kk][ty * 4]);
      float4 bv = *(const float4*)(&Bs[kk][tx * 4]);
      fma4x4(acc, av, bv);
    }
    __syncthreads();
  }
  // whole 64-col tile maps to one (part, head)
  const int part = bx >> 3;  // 0=q 1=k 2=v
  const int h = bx & 7;
  float* outp = qkv + (size_t)part * (BATCH * NH * NTOK * DH);
#pragma unroll
  for (int u = 0; u < 4; ++u) {
    int m = m0 + ty * 4 + u;
    int b = m >> 10, i = m & 1023;
    float4 val;
    val.x = acc[u][0]; val.y = acc[u][1]; val.z = acc[u][2]; val.w = acc[u][3];
    *(float4*)(outp + ((size_t)((b * NH + h) * NTOK + i)) * DH + tx * 4) = val;
  }
}

// ---------------- Kernel 2: fused attention ----------------
// One block = 64 query rows of one (b,h). Two passes over K chunks.
__global__ __launch_bounds__(256, 2) void k_attn(
    const float* __restrict__ qkv, const float* __restrict__ prob,
    const float* __restrict__ t1, const float* __restrict__ t2,
    const float* __restrict__ sita, const float* __restrict__ wt,
    const int* __restrict__ rel, const float* __restrict__ dis,
    float* __restrict__ attn0, float* __restrict__ o) {
  __shared__ float Qs[64][68];   // [d][row]
  __shared__ float Ks[64][68];   // [d][col] ; aliased as PsT[jj][row] in PV
  __shared__ float Vs[64][68];   // [jj][d]
  __shared__ float m0s[64], s0s[64], ms[64], mns[64], ss[64], thr[64], den[64];

  const int rt = blockIdx.x;   // 0..15 row tile
  const int bh = blockIdx.y;   // 0..31
  const int b = bh >> 3, h = bh & 7;
  const int i0 = rt * 64;
  const int t = threadIdx.x;
  const int tx = t & 15, ty = t >> 4;
  const float* qb = qkv + (size_t)bh * NTOK * DH;
  const float* kb = qkv + (size_t)(32 + bh) * NTOK * DH;
  const float* vb = qkv + (size_t)(64 + bh) * NTOK * DH;
  const float ita = sita[h];
  const float factor = 1.0f / (2.0f * ita * ita + 1e-6f);

  // stage Q transposed
#pragma unroll
  for (int l = 0; l < 4; ++l) {
    int idx = t + l * 256;
    int row = idx >> 4, c4 = idx & 15;
    float4 a = *(const float4*)(qb + (size_t)(i0 + row) * DH + c4 * 4);
    Qs[c4 * 4 + 0][row] = a.x; Qs[c4 * 4 + 1][row] = a.y;
    Qs[c4 * 4 + 2][row] = a.z; Qs[c4 * 4 + 3][row] = a.w;
  }
  // thresh_raw = sigmoid(q . W_thresh) * sigmoid(-2)
  {
    int row = t >> 2, dg = t & 3;
    const float* qr = qb + (size_t)(i0 + row) * DH + dg * 16;
    float sum = 0.f;
#pragma unroll
    for (int c = 0; c < 16; ++c) sum += qr[c] * wt[dg * 16 + c];
    sum += __shfl_xor(sum, 1);
    sum += __shfl_xor(sum, 2);
    if (dg == 0)
      thr[row] = (1.0f / (1.0f + expf(-sum))) * (1.0f / (1.0f + expf(2.0f)));
  }
  if (t < 64) {
    m0s[t] = -1e30f; ms[t] = -1e30f; mns[t] = 1e30f;
    s0s[t] = 0.f; ss[t] = 0.f; den[t] = 0.f;
  }
  __syncthreads();

  // ---- pass 1: online stats for dots0 (max,sum) and dots (max,min,sum) ----
  for (int j0 = 0; j0 < NTOK; j0 += 64) {
#pragma unroll
    for (int l = 0; l < 4; ++l) {
      int idx = t + l * 256;
      int row = idx >> 4, c4 = idx & 15;
      float4 a = *(const float4*)(kb + (size_t)(j0 + row) * DH + c4 * 4);
      Ks[c4 * 4 + 0][row] = a.x; Ks[c4 * 4 + 1][row] = a.y;
      Ks[c4 * 4 + 2][row] = a.z; Ks[c4 * 4 + 3][row] = a.w;
    }
    __syncthreads();
    float acc[4][4] = {};
#pragma unroll
    for (int d = 0; d < 64; ++d) {
      float4 qv = *(const float4*)(&Qs[d][ty * 4]);
      float4 kv = *(const float4*)(&Ks[d][tx * 4]);
      fma4x4(acc, qv, kv);
    }
#pragma unroll
    for (int u = 0; u < 4; ++u) {
      const int row = ty * 4 + u;
      const size_t ioff = (size_t)(i0 + row) * NTOK + j0 + tx * 4;
      int4 r4 = *(const int4*)(rel + ioff);
      float4 di4 = *(const float4*)(dis + ioff);
      int ri[4] = {r4.x, r4.y, r4.z, r4.w};
      float dd[4] = {di4.x, di4.y, di4.z, di4.w};
      float d0[4], dt[4];
#pragma unroll
      for (int v2 = 0; v2 < 4; ++v2) {
        d0[v2] = acc[u][v2] * 0.125f;
        float bias = t1[ri[v2] * 8 + h] * t2[ri[v2] * 8 + h];
        dt[v2] = d0[v2] + bias + 0.01f * expf(-factor * dd[v2]);
      }
      float cm0 = fmaxf(fmaxf(d0[0], d0[1]), fmaxf(d0[2], d0[3]));
      float cm = fmaxf(fmaxf(dt[0], dt[1]), fmaxf(dt[2], dt[3]));
      float cmn = fminf(fminf(dt[0], dt[1]), fminf(dt[2], dt[3]));
#pragma unroll
      for (int off = 1; off < 16; off <<= 1) {
        cm0 = fmaxf(cm0, __shfl_xor(cm0, off));
        cm = fmaxf(cm, __shfl_xor(cm, off));
        cmn = fminf(cmn, __shfl_xor(cmn, off));
      }
      float cs0 = 0.f, cs = 0.f;
#pragma unroll
      for (int v2 = 0; v2 < 4; ++v2) {
        cs0 += expf(d0[v2] - cm0);
        cs += expf(dt[v2] - cm);
      }
#pragma unroll
      for (int off = 1; off < 16; off <<= 1) {
        cs0 += __shfl_xor(cs0, off);
        cs += __shfl_xor(cs, off);
      }
      if (tx == 0) {
        float om0 = m0s[row], nm0 = fmaxf(om0, cm0);
        s0s[row] = s0s[row] * expf(om0 - nm0) + cs0 * expf(cm0 - nm0);
        m0s[row] = nm0;
        float om = ms[row], nm = fmaxf(om, cm);
        ss[row] = ss[row] * expf(om - nm) + cs * expf(cm - nm);
        ms[row] = nm;
        mns[row] = fminf(mns[row], cmn);
      }
    }
    __syncthreads();
  }

  // ---- finalize per-row threshold ----
  if (t < 64) {
    float inv_s = 1.0f / ss[t];
    float amax = inv_s;                       // max attn = 1/s
    float amin = expf(mns[t] - ms[t]) * inv_s;
    float th = amin + thr[t] * (amax - amin);
    if (prob[b * NTOK + i0 + t] >= 0.9f) th = 1e30f;  // record row forced to 0
    thr[t] = th;
    ss[t] = inv_s;
    s0s[t] = 1.0f / s0s[t];
  }
  __syncthreads();

  // ---- pass 2: attn0 out, pruned weights, deno, PV ----
  float oacc[4][4] = {};
  for (int j0 = 0; j0 < NTOK; j0 += 64) {
#pragma unroll
    for (int l = 0; l < 4; ++l) {
      int idx = t + l * 256;
      int row = idx >> 4, c4 = idx & 15;
      float4 a = *(const float4*)(kb + (size_t)(j0 + row) * DH + c4 * 4);
      Ks[c4 * 4 + 0][row] = a.x; Ks[c4 * 4 + 1][row] = a.y;
      Ks[c4 * 4 + 2][row] = a.z; Ks[c4 * 4 + 3][row] = a.w;
      *(float4*)(&Vs[row][c4 * 4]) =
          *(const float4*)(vb + (size_t)(j0 + row) * DH + c4 * 4);
    }
    __syncthreads();
    float acc[4][4] = {};
#pragma unroll
    for (int d = 0; d < 64; ++d) {
      float4 qv = *(const float4*)(&Qs[d][ty * 4]);
      float4 kv = *(const float4*)(&Ks[d][tx * 4]);
      fma4x4(acc, qv, kv);
    }
    float ap[4][4];
#pragma unroll
    for (int u = 0; u < 4; ++u) {
      const int row = ty * 4 + u;
      const int i = i0 + row;
      const float m0 = m0s[row], is0 = s0s[row];
      const float m = ms[row], is = ss[row], th = thr[row];
      const size_t ioff = (size_t)i * NTOK + j0 + tx * 4;
      int4 r4 = *(const int4*)(rel + ioff);
      float4 di4 = *(const float4*)(dis + ioff);
      int ri[4] = {r4.x, r4.y, r4.z, r4.w};
      float dd[4] = {di4.x, di4.y, di4.z, di4.w};
      float4 a0v;
      float aps[4];
#pragma unroll
      for (int v2 = 0; v2 < 4; ++v2) {
        float d0 = acc[u][v2] * 0.125f;
        float bias = t1[ri[v2] * 8 + h] * t2[ri[v2] * 8 + h];
        float dots = d0 + bias + 0.01f * expf(-factor * dd[v2]);
        ((float*)&a0v)[v2] = expf(d0 - m0) * is0;
        float attn = expf(dots - m) * is;
        aps[v2] = (attn - th > 0.0f) ? attn : 0.f;
      }
      *(float4*)(attn0 + (size_t)(bh * NTOK + i) * NTOK + j0 + tx * 4) = a0v;
      float dsum = aps[0] + aps[1] + aps[2] + aps[3];
#pragma unroll
      for (int off = 1; off < 16; off <<= 1) dsum += __shfl_xor(dsum, off);
      if (tx == 0) den[row] += dsum;
      ap[u][0] = aps[0]; ap[u][1] = aps[1]; ap[u][2] = aps[2]; ap[u][3] = aps[3];
    }
    __syncthreads();  // all QK reads of Ks done
    // transpose pruned weights into Ks alias: PsT[jj][row]
#pragma unroll
    for (int u = 0; u < 4; ++u)
#pragma unroll
      for (int v2 = 0; v2 < 4; ++v2) Ks[tx * 4 + v2][ty * 4 + u] = ap[u][v2];
    __syncthreads();
#pragma unroll
    for (int jj = 0; jj < 64; ++jj) {
      float4 pv = *(const float4*)(&Ks[jj][ty * 4]);
      float4 vv = *(const float4*)(&Vs[jj][tx * 4]);
      fma4x4(oacc, pv, vv);
    }
    __syncthreads();  // before next chunk staging
  }
  // scale by 1/(deno+1e-6) and store o in (b,n,h,d)
#pragma unroll
  for (int u = 0; u < 4; ++u) {
    const int row = ty * 4 + u;
    const int i = i0 + row;
    const float pf = 1.0f / (den[row] + 1e-6f);
    float4 ov;
    ov.x = oacc[u][0] * pf; ov.y = oacc[u][1] * pf;
    ov.z = oacc[u][2] * pf; ov.w = oacc[u][3] * pf;
    *(float4*)(o + (((size_t)b * NTOK + i) * NH + h) * DH + tx * 4) = ov;
  }
}

// ---------------- Kernel 3: output GEMM ----------------
__global__ __launch_bounds__(256) void k_out(const float* __restrict__ a,
                                             const float* __restrict__ w,
                                             const float* __restrict__ bias,
                                             float* __restrict__ c) {
  __shared__ float As[32][68];
  __shared__ float Bs[32][68];
  const int bx = blockIdx.x;  // 0..7
  const int by = blockIdx.y;  // 0..63
  const int t = threadIdx.x;
  const int tx = t & 15, ty = t >> 4;
  const int m0 = by * 64, n0 = bx * 64;
  float acc[4][4] = {};
  for (int k0 = 0; k0 < 512; k0 += 32) {
#pragma unroll
    for (int l = 0; l < 2; ++l) {
      int idx = t + l * 256;
      {
        int row = idx >> 3, c4 = idx & 7;
        float4 av = *(const float4*)(a + (size_t)(m0 + row) * 512 + k0 + c4 * 4);
        As[c4 * 4 + 0][row] = av.x; As[c4 * 4 + 1][row] = av.y;
        As[c4 * 4 + 2][row] = av.z; As[c4 * 4 + 3][row] = av.w;
      }
      {
        int row = idx >> 4, c4 = idx & 15;
        *(float4*)(&Bs[row][c4 * 4]) =
            *(const float4*)(w + (size_t)(k0 + row) * 512 + n0 + c4 * 4);
      }
    }
    __syncthreads();
#pragma unroll
    for (int kk = 0; kk < 32; ++kk) {
      float4 av = *(const float4*)(&As[kk][ty * 4]);
      float4 bv = *(const float4*)(&Bs[kk][tx * 4]);
      fma4x4(acc, av, bv);
    }
    __syncthreads();
  }
  float4 bv4 = *(const float4*)(bias + n0 + tx * 4);
#pragma unroll
  for (int u = 0; u < 4; ++u) {
    int m = m0 + ty * 4 + u;
    float4 val;
    val.x = acc[u][0] + bv4.x; val.y = acc[u][1] + bv4.y;
    val.z = acc[u][2] + bv4.z; val.w = acc[u][3] + bv4.w;
    *(float4*)(c + (size_t)m * 512 + n0 + tx * 4) = val;
  }
}

extern "C" void kernel_launch(void* const* d_in, const int* in_sizes, int n_in,
                              void* d_out, int out_size, void* d_ws, size_t ws_size,
                              hipStream_t stream) {
  const float* x    = (const float*)d_in[0];
  const float* prob = (const float*)d_in[1];
  const float* wqkv = (const float*)d_in[2];
  const float* t1   = (const float*)d_in[3];
  const float* t2   = (const float*)d_in[4];
  const float* sita = (const float*)d_in[5];
  const float* wt   = (const float*)d_in[6];
  const float* wout = (const float*)d_in[7];
  const float* bout = (const float*)d_in[8];
  const int*   rel  = (const int*)d_in[9];
  const float* dis  = (const float*)d_in[10];

  float* out = (float*)d_out;
  float* attn0 = out + (size_t)BATCH * NTOK * 512;
  float* qkv = (float*)d_ws;                              // 3 * 2097152 floats
  float* o = qkv + (size_t)3 * BATCH * NH * NTOK * DH;    // 2097152 floats

  hipLaunchKernelGGL(k_qkv, dim3(24, 64), dim3(256), 0, stream, x, wqkv, qkv);
  hipLaunchKernelGGL(k_attn, dim3(16, 32), dim3(256), 0, stream,
                     qkv, prob, t1, t2, sita, wt, rel, dis, attn0, o);
  hipLaunchKernelGGL(k_out, dim3(8, 64), dim3(256), 0, stream, o, wout, bout, out);
}

// Round 2
// 542.197 us; speedup vs baseline: 10.2679x; 10.2679x over previous
//
#include <hip/hip_runtime.h>
#include <cmath>

#define NTOK 1024
#define NH 8
#define DH 64
#define DIM 512
#define BATCH 4
#define TBL 3969  // 63*63

__device__ __forceinline__ void fma4x4(float acc[4][4], const float4& av, const float4& bv) {
  const float a4[4] = {av.x, av.y, av.z, av.w};
  const float b4[4] = {bv.x, bv.y, bv.z, bv.w};
#pragma unroll
  for (int u = 0; u < 4; ++u)
#pragma unroll
    for (int v = 0; v < 4; ++v) acc[u][v] += a4[u] * b4[v];
}

// ---------------- Kernel 0: combined RPE table ----------------
// comb[h][(dy+31)*63 + (dx+31)] = t1*t2 + 0.01*exp(-factor_h * dis(dy,dx))
// dis read from the provided input at a representative (i,j) -> bitwise-safe.
__global__ void k_comb(const float* __restrict__ t1, const float* __restrict__ t2,
                       const float* __restrict__ sita, const float* __restrict__ dis,
                       float* __restrict__ comb) {
  int idx = blockIdx.x * 256 + threadIdx.x;
  if (idx >= TBL) return;
  int dy = idx / 63 - 31, dx = idx % 63 - 31;
  int yi = dy > 0 ? dy : 0, yj = dy > 0 ? 0 : -dy;
  int xi = dx > 0 ? dx : 0, xj = dx > 0 ? 0 : -dx;
  float dv = dis[(size_t)(yi * 32 + xi) * NTOK + (yj * 32 + xj)];
  float bias = t1[idx * 8] * t2[idx * 8];  // h=0 handled in loop below
#pragma unroll
  for (int h = 0; h < NH; ++h) {
    float ita = sita[h];
    float factor = 1.0f / (2.0f * ita * ita + 1e-6f);
    float bi = t1[idx * 8 + h] * t2[idx * 8 + h];
    comb[(size_t)h * TBL + idx] = bi + 0.01f * expf(-factor * dv);
  }
  (void)bias;
}

// ---------------- Kernel 1: QKV GEMM ----------------
__global__ __launch_bounds__(256) void k_qkv(const float* __restrict__ x,
                                             const float* __restrict__ w,
                                             float* __restrict__ qkv) {
  __shared__ float As[32][68];
  __shared__ float Bs[32][68];
  const int bx = blockIdx.x;  // 0..23
  const int by = blockIdx.y;  // 0..63
  const int t = threadIdx.x;
  const int tx = t & 15, ty = t >> 4;
  const int m0 = by * 64, n0 = bx * 64;
  float acc[4][4] = {};
  for (int k0 = 0; k0 < 512; k0 += 32) {
#pragma unroll
    for (int l = 0; l < 2; ++l) {
      int idx = t + l * 256;
      {
        int row = idx >> 3, c4 = idx & 7;
        float4 a = *(const float4*)(x + (size_t)(m0 + row) * 512 + k0 + c4 * 4);
        As[c4 * 4 + 0][row] = a.x; As[c4 * 4 + 1][row] = a.y;
        As[c4 * 4 + 2][row] = a.z; As[c4 * 4 + 3][row] = a.w;
      }
      {
        int row = idx >> 4, c4 = idx & 15;
        *(float4*)(&Bs[row][c4 * 4]) =
            *(const float4*)(w + (size_t)(k0 + row) * 1536 + n0 + c4 * 4);
      }
    }
    __syncthreads();
#pragma unroll
    for (int kk = 0; kk < 32; ++kk) {
      float4 av = *(const float4*)(&As[kk][ty * 4]);
      float4 bv = *(const float4*)(&Bs[kk][tx * 4]);
      fma4x4(acc, av, bv);
    }
    __syncthreads();
  }
  const int part = bx >> 3;
  const int h = bx & 7;
  float* outp = qkv + (size_t)part * (BATCH * NH * NTOK * DH);
#pragma unroll
  for (int u = 0; u < 4; ++u) {
    int m = m0 + ty * 4 + u;
    int b = m >> 10, i = m & 1023;
    float4 val;
    val.x = acc[u][0]; val.y = acc[u][1]; val.z = acc[u][2]; val.w = acc[u][3];
    *(float4*)(outp + ((size_t)((b * NH + h) * NTOK + i)) * DH + tx * 4) = val;
  }
}

// ---------------- Kernel 2: fused attention ----------------
__global__ __launch_bounds__(256, 2) void k_attn(
    const float* __restrict__ qkv, const float* __restrict__ prob,
    const float* __restrict__ comb, const float* __restrict__ wt,
    float* __restrict__ attn0, float* __restrict__ o) {
  __shared__ float Qs[64][68];   // [d][row], pre-scaled by 0.125
  __shared__ float Ks[64][68];   // [d][col]
  __shared__ float Vs[64][68];   // [jj][d]
  __shared__ float Ps[64][68];   // [jj][row] pruned weights (transposed)
  __shared__ float cmbs[3][64];  // comb slice for current j-tile
  __shared__ float m0s[64], is0s[64], ms[64], iss[64], thr[64];

  const int rt = blockIdx.x;   // 0..15
  const int bh = blockIdx.y;   // 0..31
  const int b = bh >> 3, h = bh & 7;
  const int i0 = rt * 64;
  const int t = threadIdx.x;
  const int tx = t & 15, ty = t >> 4;
  const float* qb = qkv + (size_t)bh * NTOK * DH;
  const float* kb = qkv + (size_t)(32 + bh) * NTOK * DH;
  const float* vb = qkv + (size_t)(64 + bh) * NTOK * DH;
  const float* ch = comb + (size_t)h * TBL;

  // stage Q transposed, pre-scaled by 2^-3 (exact)
#pragma unroll
  for (int l = 0; l < 4; ++l) {
    int idx = t + l * 256;
    int row = idx >> 4, c4 = idx & 15;
    float4 a = *(const float4*)(qb + (size_t)(i0 + row) * DH + c4 * 4);
    Qs[c4 * 4 + 0][row] = a.x * 0.125f; Qs[c4 * 4 + 1][row] = a.y * 0.125f;
    Qs[c4 * 4 + 2][row] = a.z * 0.125f; Qs[c4 * 4 + 3][row] = a.w * 0.125f;
  }
  // thresh_raw = sigmoid(q . W_thresh) * sigmoid(-2)   (uses UNscaled q)
  {
    int row = t >> 2, dg = t & 3;
    const float* qr = qb + (size_t)(i0 + row) * DH + dg * 16;
    float sum = 0.f;
#pragma unroll
    for (int c = 0; c < 16; ++c) sum += qr[c] * wt[dg * 16 + c];
    sum += __shfl_xor(sum, 1);
    sum += __shfl_xor(sum, 2);
    if (dg == 0)
      thr[row] = (1.0f / (1.0f + expf(-sum))) * (1.0f / (1.0f + expf(2.0f)));
  }
  __syncthreads();

  // per-lane online stats (per u => per query row)
  float m0l[4], s0l[4], ml[4], sl[4], mnl[4];
#pragma unroll
  for (int u = 0; u < 4; ++u) {
    m0l[u] = -1e30f; ml[u] = -1e30f; mnl[u] = 1e30f;
    s0l[u] = 0.f; sl[u] = 0.f;
  }
  const int rbase = (i0 >> 5) + 30;  // (dy+31) base before subtracting (j0>>5)+(jj>>5)

  // ---- pass 1 ----
#pragma unroll 1
  for (int j0 = 0; j0 < NTOK; j0 += 64) {
#pragma unroll
    for (int l = 0; l < 4; ++l) {
      int idx = t + l * 256;
      int row = idx >> 4, c4 = idx & 15;
      float4 a = *(const float4*)(kb + (size_t)(j0 + row) * DH + c4 * 4);
      Ks[c4 * 4 + 0][row] = a.x; Ks[c4 * 4 + 1][row] = a.y;
      Ks[c4 * 4 + 2][row] = a.z; Ks[c4 * 4 + 3][row] = a.w;
    }
    if (t < 192) {
      int l = t >> 6, c = t & 63;
      if (c < 63) cmbs[l][c] = ch[(rbase - (j0 >> 5) + l) * 63 + c];
    }
    __syncthreads();
    float acc[4][4] = {};
#pragma unroll
    for (int d = 0; d < 64; ++d) {
      float4 qv = *(const float4*)(&Qs[d][ty * 4]);
      float4 kv = *(const float4*)(&Ks[d][tx * 4]);
      fma4x4(acc, qv, kv);
    }
    const int jj0 = tx * 4;
#pragma unroll
    for (int u = 0; u < 4; ++u) {
      const int row = ty * 4 + u;
      const int rl = (row >> 5) - (jj0 >> 5) + 1;
      const int cb = (row & 31) - (jj0 & 31) + 31;
      float dt[4];
#pragma unroll
      for (int v2 = 0; v2 < 4; ++v2) dt[v2] = acc[u][v2] + cmbs[rl][cb - v2];
      float t0 = fmaxf(fmaxf(acc[u][0], acc[u][1]), fmaxf(acc[u][2], acc[u][3]));
      float tt = fmaxf(fmaxf(dt[0], dt[1]), fmaxf(dt[2], dt[3]));
      float tmn = fminf(fminf(dt[0], dt[1]), fminf(dt[2], dt[3]));
      float nm0 = fmaxf(m0l[u], t0);
      s0l[u] = s0l[u] * expf(m0l[u] - nm0) + expf(acc[u][0] - nm0) +
               expf(acc[u][1] - nm0) + expf(acc[u][2] - nm0) + expf(acc[u][3] - nm0);
      m0l[u] = nm0;
      float nm = fmaxf(ml[u], tt);
      sl[u] = sl[u] * expf(ml[u] - nm) + expf(dt[0] - nm) + expf(dt[1] - nm) +
              expf(dt[2] - nm) + expf(dt[3] - nm);
      ml[u] = nm;
      mnl[u] = fminf(mnl[u], tmn);
    }
    __syncthreads();
  }

  // cross-lane combine over the 16 tx lanes, then finalize per-row values
#pragma unroll
  for (int u = 0; u < 4; ++u) {
    float m0 = m0l[u], s0 = s0l[u], m = ml[u], s = sl[u], mn = mnl[u];
#pragma unroll
    for (int off = 1; off < 16; off <<= 1) {
      float om0 = __shfl_xor(m0, off), os0 = __shfl_xor(s0, off);
      float nm0 = fmaxf(m0, om0);
      s0 = s0 * expf(m0 - nm0) + os0 * expf(om0 - nm0);
      m0 = nm0;
      float om = __shfl_xor(m, off), os = __shfl_xor(s, off);
      float nm = fmaxf(m, om);
      s = s * expf(m - nm) + os * expf(om - nm);
      m = nm;
      mn = fminf(mn, __shfl_xor(mn, off));
    }
    if (tx == 0) {
      int row = ty * 4 + u;
      float inv = 1.0f / s;
      float amin = expf(mn - m) * inv;
      float th = amin + thr[row] * (inv - amin);
      if (prob[b * NTOK + i0 + row] >= 0.9f) th = 1e30f;
      m0s[row] = m0; is0s[row] = 1.0f / s0;
      ms[row] = m; iss[row] = inv; thr[row] = th;
    }
  }
  __syncthreads();

  // ---- pass 2 ----
  float oacc[4][4] = {};
  float denl[4] = {0.f, 0.f, 0.f, 0.f};
#pragma unroll 1
  for (int j0 = 0; j0 < NTOK; j0 += 64) {
#pragma unroll
    for (int l = 0; l < 4; ++l) {
      int idx = t + l * 256;
      int row = idx >> 4, c4 = idx & 15;
      float4 a = *(const float4*)(kb + (size_t)(j0 + row) * DH + c4 * 4);
      Ks[c4 * 4 + 0][row] = a.x; Ks[c4 * 4 + 1][row] = a.y;
      Ks[c4 * 4 + 2][row] = a.z; Ks[c4 * 4 + 3][row] = a.w;
      *(float4*)(&Vs[row][c4 * 4]) =
          *(const float4*)(vb + (size_t)(j0 + row) * DH + c4 * 4);
    }
    if (t < 192) {
      int l = t >> 6, c = t & 63;
      if (c < 63) cmbs[l][c] = ch[(rbase - (j0 >> 5) + l) * 63 + c];
    }
    __syncthreads();
    float acc[4][4] = {};
#pragma unroll
    for (int d = 0; d < 64; ++d) {
      float4 qv = *(const float4*)(&Qs[d][ty * 4]);
      float4 kv = *(const float4*)(&Ks[d][tx * 4]);
      fma4x4(acc, qv, kv);
    }
    const int jj0 = tx * 4;
#pragma unroll
    for (int u = 0; u < 4; ++u) {
      const int row = ty * 4 + u;
      const int i = i0 + row;
      const int rl = (row >> 5) - (jj0 >> 5) + 1;
      const int cb = (row & 31) - (jj0 & 31) + 31;
      const float m0 = m0s[row], is0 = is0s[row];
      const float m = ms[row], is = iss[row], th = thr[row];
      float4 a0v;
      float aps[4];
#pragma unroll
      for (int v2 = 0; v2 < 4; ++v2) {
        float d0 = acc[u][v2];
        float dts = d0 + cmbs[rl][cb - v2];
        ((float*)&a0v)[v2] = expf(d0 - m0) * is0;
        float attn = expf(dts - m) * is;
        aps[v2] = (attn - th > 0.0f) ? attn : 0.f;
      }
      *(float4*)(attn0 + (size_t)(bh * NTOK + i) * NTOK + j0 + jj0) = a0v;
      denl[u] += (aps[0] + aps[1]) + (aps[2] + aps[3]);
#pragma unroll
      for (int v2 = 0; v2 < 4; ++v2) Ps[jj0 + v2][row] = aps[v2];
    }
    __syncthreads();  // Ps/Vs complete, Ks reads done
#pragma unroll
    for (int jj = 0; jj < 64; ++jj) {
      float4 pv = *(const float4*)(&Ps[jj][ty * 4]);
      float4 vv = *(const float4*)(&Vs[jj][tx * 4]);
      fma4x4(oacc, pv, vv);
    }
    __syncthreads();
  }
  // reduce deno across tx lanes, scale, store o in (b,n,h,d)
#pragma unroll
  for (int u = 0; u < 4; ++u) {
#pragma unroll
    for (int off = 1; off < 16; off <<= 1) denl[u] += __shfl_xor(denl[u], off);
    const int row = ty * 4 + u;
    const int i = i0 + row;
    const float pf = 1.0f / (denl[u] + 1e-6f);
    float4 ov;
    ov.x = oacc[u][0] * pf; ov.y = oacc[u][1] * pf;
    ov.z = oacc[u][2] * pf; ov.w = oacc[u][3] * pf;
    *(float4*)(o + (((size_t)b * NTOK + i) * NH + h) * DH + tx * 4) = ov;
  }
}

// ---------------- Kernel 3: output GEMM ----------------
__global__ __launch_bounds__(256) void k_out(const float* __restrict__ a,
                                             const float* __restrict__ w,
                                             const float* __restrict__ bias,
                                             float* __restrict__ c) {
  __shared__ float As[32][68];
  __shared__ float Bs[32][68];
  const int bx = blockIdx.x;
  const int by = blockIdx.y;
  const int t = threadIdx.x;
  const int tx = t & 15, ty = t >> 4;
  const int m0 = by * 64, n0 = bx * 64;
  float acc[4][4] = {};
  for (int k0 = 0; k0 < 512; k0 += 32) {
#pragma unroll
    for (int l = 0; l < 2; ++l) {
      int idx = t + l * 256;
      {
        int row = idx >> 3, c4 = idx & 7;
        float4 av = *(const float4*)(a + (size_t)(m0 + row) * 512 + k0 + c4 * 4);
        As[c4 * 4 + 0][row] = av.x; As[c4 * 4 + 1][row] = av.y;
        As[c4 * 4 + 2][row] = av.z; As[c4 * 4 + 3][row] = av.w;
      }
      {
        int row = idx >> 4, c4 = idx & 15;
        *(float4*)(&Bs[row][c4 * 4]) =
            *(const float4*)(w + (size_t)(k0 + row) * 512 + n0 + c4 * 4);
      }
    }
    __syncthreads();
#pragma unroll
    for (int kk = 0; kk < 32; ++kk) {
      float4 av = *(const float4*)(&As[kk][ty * 4]);
      float4 bv = *(const float4*)(&Bs[kk][tx * 4]);
      fma4x4(acc, av, bv);
    }
    __syncthreads();
  }
  float4 bv4 = *(const float4*)(bias + n0 + tx * 4);
#pragma unroll
  for (int u = 0; u < 4; ++u) {
    int m = m0 + ty * 4 + u;
    float4 val;
    val.x = acc[u][0] + bv4.x; val.y = acc[u][1] + bv4.y;
    val.z = acc[u][2] + bv4.z; val.w = acc[u][3] + bv4.w;
    *(float4*)(c + (size_t)m * 512 + n0 + tx * 4) = val;
  }
}

extern "C" void kernel_launch(void* const* d_in, const int* in_sizes, int n_in,
                              void* d_out, int out_size, void* d_ws, size_t ws_size,
                              hipStream_t stream) {
  const float* x    = (const float*)d_in[0];
  const float* prob = (const float*)d_in[1];
  const float* wqkv = (const float*)d_in[2];
  const float* t1   = (const float*)d_in[3];
  const float* t2   = (const float*)d_in[4];
  const float* sita = (const float*)d_in[5];
  const float* wt   = (const float*)d_in[6];
  const float* wout = (const float*)d_in[7];
  const float* bout = (const float*)d_in[8];
  const float* dis  = (const float*)d_in[10];

  float* out = (float*)d_out;
  float* attn0 = out + (size_t)BATCH * NTOK * 512;
  float* comb = (float*)d_ws;                         // 31752 floats (pad to 32768)
  float* qkv = comb + 32768;                          // 3 * 2097152 floats
  float* o = qkv + (size_t)3 * BATCH * NH * NTOK * DH;  // 2097152 floats

  hipLaunchKernelGGL(k_comb, dim3(16), dim3(256), 0, stream, t1, t2, sita, dis, comb);
  hipLaunchKernelGGL(k_qkv, dim3(24, 64), dim3(256), 0, stream, x, wqkv, qkv);
  hipLaunchKernelGGL(k_attn, dim3(16, 32), dim3(256), 0, stream,
                     qkv, prob, comb, wt, attn0, o);
  hipLaunchKernelGGL(k_out, dim3(8, 64), dim3(256), 0, stream, o, wout, bout, out);
}

// Round 3
// 399.464 us; speedup vs baseline: 13.9368x; 1.3573x over previous
//
#include <hip/hip_runtime.h>
#include <cmath>

#define NTOK 1024
#define NH 8
#define DH 64
#define BATCH 4
#define TBL 3969  // 63*63

typedef __attribute__((ext_vector_type(8))) short short8;
typedef __attribute__((ext_vector_type(4))) float f32x4;

__device__ __forceinline__ unsigned bf16rne(float x) {
  unsigned u = __float_as_uint(x);
  return (u + 0x7fffu + ((u >> 16) & 1u)) >> 16;
}

__device__ __forceinline__ void split8(const float* v, short8& h8, short8& l8) {
#pragma unroll
  for (int j = 0; j < 8; ++j) {
    unsigned h = bf16rne(v[j]);
    float r = v[j] - __uint_as_float(h << 16);
    unsigned l = bf16rne(r);
    h8[j] = (short)h;
    l8[j] = (short)l;
  }
}

__device__ __forceinline__ f32x4 mfma16(short8 a, short8 b, f32x4 c) {
  return __builtin_amdgcn_mfma_f32_16x16x32_bf16(a, b, c, 0, 0, 0);
}

__device__ __forceinline__ void fma4x4(float acc[4][4], const float4& av, const float4& bv) {
  const float a4[4] = {av.x, av.y, av.z, av.w};
  const float b4[4] = {bv.x, bv.y, bv.z, bv.w};
#pragma unroll
  for (int u = 0; u < 4; ++u)
#pragma unroll
    for (int v = 0; v < 4; ++v) acc[u][v] += a4[u] * b4[v];
}

// ---------------- Kernel 0: combined RPE table (+ exp table) ----------------
__global__ void k_comb(const float* __restrict__ t1, const float* __restrict__ t2,
                       const float* __restrict__ sita, const float* __restrict__ dis,
                       float* __restrict__ comb, float* __restrict__ combe) {
  int idx = blockIdx.x * 256 + threadIdx.x;
  if (idx >= TBL) return;
  int dy = idx / 63 - 31, dx = idx % 63 - 31;
  int yi = dy > 0 ? dy : 0, yj = dy > 0 ? 0 : -dy;
  int xi = dx > 0 ? dx : 0, xj = dx > 0 ? 0 : -dx;
  float dv = dis[(size_t)(yi * 32 + xi) * NTOK + (yj * 32 + xj)];
#pragma unroll
  for (int h = 0; h < NH; ++h) {
    float ita = sita[h];
    float factor = 1.0f / (2.0f * ita * ita + 1e-6f);
    float bi = t1[idx * 8 + h] * t2[idx * 8 + h];
    float v = bi + 0.01f * expf(-factor * dv);
    comb[(size_t)h * TBL + idx] = v;
    combe[(size_t)h * TBL + idx] = expf(v);
  }
}

// ---------------- Kernel 1: QKV GEMM (fp32) ----------------
__global__ __launch_bounds__(256) void k_qkv(const float* __restrict__ x,
                                             const float* __restrict__ w,
                                             float* __restrict__ qkv) {
  __shared__ float As[32][68];
  __shared__ float Bs[32][68];
  const int bx = blockIdx.x;  // 0..23
  const int by = blockIdx.y;  // 0..63
  const int t = threadIdx.x;
  const int tx = t & 15, ty = t >> 4;
  const int m0 = by * 64, n0 = bx * 64;
  float acc[4][4] = {};
  for (int k0 = 0; k0 < 512; k0 += 32) {
#pragma unroll
    for (int l = 0; l < 2; ++l) {
      int idx = t + l * 256;
      {
        int row = idx >> 3, c4 = idx & 7;
        float4 a = *(const float4*)(x + (size_t)(m0 + row) * 512 + k0 + c4 * 4);
        As[c4 * 4 + 0][row] = a.x; As[c4 * 4 + 1][row] = a.y;
        As[c4 * 4 + 2][row] = a.z; As[c4 * 4 + 3][row] = a.w;
      }
      {
        int row = idx >> 4, c4 = idx & 15;
        *(float4*)(&Bs[row][c4 * 4]) =
            *(const float4*)(w + (size_t)(k0 + row) * 1536 + n0 + c4 * 4);
      }
    }
    __syncthreads();
#pragma unroll
    for (int kk = 0; kk < 32; ++kk) {
      float4 av = *(const float4*)(&As[kk][ty * 4]);
      float4 bv = *(const float4*)(&Bs[kk][tx * 4]);
      fma4x4(acc, av, bv);
    }
    __syncthreads();
  }
  const int part = bx >> 3;
  const int h = bx & 7;
  float* outp = qkv + (size_t)part * (BATCH * NH * NTOK * DH);
#pragma unroll
  for (int u = 0; u < 4; ++u) {
    int m = m0 + ty * 4 + u;
    int b = m >> 10, i = m & 1023;
    float4 val;
    val.x = acc[u][0]; val.y = acc[u][1]; val.z = acc[u][2]; val.w = acc[u][3];
    *(float4*)(outp + ((size_t)((b * NH + h) * NTOK + i)) * DH + tx * 4) = val;
  }
}

// ---------------- Kernel 2: fused attention (split-bf16 MFMA) ----------------
__global__ __launch_bounds__(256, 2) void k_attn(
    const float* __restrict__ qkv, const float* __restrict__ prob,
    const float* __restrict__ comb, const float* __restrict__ combe,
    const float* __restrict__ wt,
    float* __restrict__ attn0, float* __restrict__ o) {
  __shared__ unsigned short KhS[64 * 72], KlS[64 * 72];  // K [token][d] bf16 hi/lo
  __shared__ unsigned short VhS[64 * 72], VlS[64 * 72];  // V^T [d][jj] swizzled bf16
  __shared__ float PfS[64 * 68];                         // P [row][jj] fp32
  __shared__ float2 csS[3 * 64];                         // (comb, exp(comb)) slice
  __shared__ float thrS[64];

  const int rt = blockIdx.x;   // 0..15 row tile
  const int bh = blockIdx.y;   // 0..31
  const int b = bh >> 3, h = bh & 7;
  const int i0 = rt * 64;
  const int t = threadIdx.x;
  const int w = t >> 6;        // wave 0..3 -> rows 16w..16w+15
  const int lane = t & 63;
  const int q = lane >> 4, li = lane & 15;
  const float* qb = qkv + (size_t)bh * NTOK * DH;
  const float* kb = qkv + (size_t)(32 + bh) * NTOK * DH;
  const float* vb = qkv + (size_t)(64 + bh) * NTOK * DH;
  const float* ch = comb + (size_t)h * TBL;
  const float* che = combe + (size_t)h * TBL;
  const int rbase = (i0 >> 5) + 30;

  // thresh_raw = sigmoid(q . W_thresh) * sigmoid(-2)
  {
    int row = t >> 2, dg = t & 3;
    const float* qr2 = qb + (size_t)(i0 + row) * DH + dg * 16;
    float sum = 0.f;
#pragma unroll
    for (int c = 0; c < 16; ++c) sum += qr2[c] * wt[dg * 16 + c];
    sum += __shfl_xor(sum, 1);
    sum += __shfl_xor(sum, 2);
    if (dg == 0)
      thrS[row] = (1.0f / (1.0f + expf(-sum))) * (1.0f / (1.0f + expf(2.0f)));
  }

  // Q fragments straight from global (A-layout: m=li, k=32c+8q+j), prescaled 0.125
  short8 qah[2], qal[2];
  {
    const float* qr2 = qb + (size_t)(i0 + 16 * w + li) * DH;
#pragma unroll
    for (int c = 0; c < 2; ++c) {
      float4 a = *(const float4*)(qr2 + 32 * c + 8 * q);
      float4 bb = *(const float4*)(qr2 + 32 * c + 8 * q + 4);
      float tmp[8] = {a.x * 0.125f, a.y * 0.125f, a.z * 0.125f, a.w * 0.125f,
                      bb.x * 0.125f, bb.y * 0.125f, bb.z * 0.125f, bb.w * 0.125f};
      split8(tmp, qah[c], qal[c]);
    }
  }

  // per-lane online stats, indexed by r (row_local = 16w + 4q + r)
  float m0l[4], s0l[4], ml[4], sl[4], mnl[4];
#pragma unroll
  for (int r = 0; r < 4; ++r) {
    m0l[r] = -1e30f; ml[r] = -1e30f; mnl[r] = 1e30f;
    s0l[r] = 0.f; sl[r] = 0.f;
  }

  // ================= pass 1: stats =================
#pragma unroll 1
  for (int j0 = 0; j0 < NTOK; j0 += 64) {
#pragma unroll
    for (int l = 0; l < 4; ++l) {  // stage K -> bf16 hi/lo
      int idx = t + l * 256;
      int n = idx >> 4, d0 = (idx & 15) * 4;
      float4 a = *(const float4*)(kb + (size_t)(j0 + n) * DH + d0);
      float av[4] = {a.x, a.y, a.z, a.w};
      unsigned hh[4], ll[4];
#pragma unroll
      for (int cI = 0; cI < 4; ++cI) {
        hh[cI] = bf16rne(av[cI]);
        float r = av[cI] - __uint_as_float(hh[cI] << 16);
        ll[cI] = bf16rne(r);
      }
      *(uint2*)(KhS + n * 72 + d0) = make_uint2(hh[0] | (hh[1] << 16), hh[2] | (hh[3] << 16));
      *(uint2*)(KlS + n * 72 + d0) = make_uint2(ll[0] | (ll[1] << 16), ll[2] | (ll[3] << 16));
    }
    if (t < 192) {
      int rl2 = t >> 6, c2 = t & 63;
      if (c2 < 63) {
        int off = (rbase - (j0 >> 5) + rl2) * 63 + c2;
        csS[rl2 * 64 + c2] = make_float2(ch[off], che[off]);
      }
    }
    __syncthreads();

    f32x4 acc[4] = {};
#pragma unroll
    for (int c = 0; c < 2; ++c) {
#pragma unroll
      for (int T = 0; T < 4; ++T) {
        short8 bh8 = *(const short8*)(KhS + (16 * T + li) * 72 + 32 * c + 8 * q);
        short8 bl8 = *(const short8*)(KlS + (16 * T + li) * 72 + 32 * c + 8 * q);
        acc[T] = mfma16(qah[c], bh8, acc[T]);
        acc[T] = mfma16(qah[c], bl8, acc[T]);
        acc[T] = mfma16(qal[c], bh8, acc[T]);
      }
    }

    float2 ce[4][4];
    float t0[4], tt[4], tmn[4];
#pragma unroll
    for (int r = 0; r < 4; ++r) { t0[r] = -1e30f; tt[r] = -1e30f; tmn[r] = 1e30f; }
#pragma unroll
    for (int T = 0; T < 4; ++T) {
      int jj = 16 * T + li;
#pragma unroll
      for (int r = 0; r < 4; ++r) {
        int il = 16 * w + 4 * q + r;
        int rl2 = (il >> 5) - (jj >> 5) + 1;
        int cc2 = (il & 31) - (jj & 31) + 31;
        ce[T][r] = csS[rl2 * 64 + cc2];
        float d0 = acc[T][r];
        float dt = d0 + ce[T][r].x;
        t0[r] = fmaxf(t0[r], d0);
        tt[r] = fmaxf(tt[r], dt);
        tmn[r] = fminf(tmn[r], dt);
      }
    }
#pragma unroll
    for (int r = 0; r < 4; ++r) {
      float nm0 = fmaxf(m0l[r], t0[r]);
      float nm = fmaxf(ml[r], tt[r]);
      float sc0 = expf(m0l[r] - nm0), sc = expf(ml[r] - nm), k0 = expf(nm0 - nm);
      float s0a = 0.f, sEa = 0.f;
#pragma unroll
      for (int T = 0; T < 4; ++T) {
        float e0 = expf(acc[T][r] - nm0);
        s0a += e0;
        sEa += e0 * ce[T][r].y;
      }
      s0l[r] = s0l[r] * sc0 + s0a;
      sl[r] = sl[r] * sc + sEa * k0;
      m0l[r] = nm0; ml[r] = nm; mnl[r] = fminf(mnl[r], tmn[r]);
    }
    __syncthreads();
  }

  // ================= finalize per-row =================
  float m0f[4], is0f[4], thf[4], crf[4];
#pragma unroll
  for (int r = 0; r < 4; ++r) {
    float m0 = m0l[r], s0 = s0l[r], m = ml[r], s = sl[r], mn = mnl[r];
#pragma unroll
    for (int off = 1; off < 16; off <<= 1) {
      float om = __shfl_xor(m0, off), os = __shfl_xor(s0, off);
      float n0 = fmaxf(m0, om);
      s0 = s0 * expf(m0 - n0) + os * expf(om - n0);
      m0 = n0;
      float om2 = __shfl_xor(m, off), os2 = __shfl_xor(s, off);
      float n2 = fmaxf(m, om2);
      s = s * expf(m - n2) + os2 * expf(om2 - n2);
      m = n2;
      mn = fminf(mn, __shfl_xor(mn, off));
    }
    float isf = 1.f / s;
    float amin = expf(mn - m) * isf;
    int rloc = 16 * w + 4 * q + r;
    float th = amin + thrS[rloc] * (isf - amin);
    if (prob[b * NTOK + i0 + rloc] >= 0.9f) th = 1e30f;
    m0f[r] = m0; is0f[r] = 1.f / s0; thf[r] = th; crf[r] = expf(m0 - m) * isf;
  }

  // ================= pass 2: attn0, P, PV =================
  f32x4 oacc[4] = {};
  float denl[4] = {0.f, 0.f, 0.f, 0.f};
#pragma unroll 1
  for (int j0 = 0; j0 < NTOK; j0 += 64) {
#pragma unroll
    for (int l = 0; l < 4; ++l) {  // stage K (identical to pass 1)
      int idx = t + l * 256;
      int n = idx >> 4, d0 = (idx & 15) * 4;
      float4 a = *(const float4*)(kb + (size_t)(j0 + n) * DH + d0);
      float av[4] = {a.x, a.y, a.z, a.w};
      unsigned hh[4], ll[4];
#pragma unroll
      for (int cI = 0; cI < 4; ++cI) {
        hh[cI] = bf16rne(av[cI]);
        float r = av[cI] - __uint_as_float(hh[cI] << 16);
        ll[cI] = bf16rne(r);
      }
      *(uint2*)(KhS + n * 72 + d0) = make_uint2(hh[0] | (hh[1] << 16), hh[2] | (hh[3] << 16));
      *(uint2*)(KlS + n * 72 + d0) = make_uint2(ll[0] | (ll[1] << 16), ll[2] | (ll[3] << 16));
    }
#pragma unroll
    for (int l = 0; l < 2; ++l) {  // stage V^T swizzled bf16 hi/lo
      int idx = t + l * 256;
      int pr = idx >> 4, d0 = (idx & 15) * 4;
      int jj0 = pr * 2;
      float4 a = *(const float4*)(vb + (size_t)(j0 + jj0) * DH + d0);
      float4 bb = *(const float4*)(vb + (size_t)(j0 + jj0 + 1) * DH + d0);
      float av[4] = {a.x, a.y, a.z, a.w}, bv[4] = {bb.x, bb.y, bb.z, bb.w};
#pragma unroll
      for (int cI = 0; cI < 4; ++cI) {
        int d = d0 + cI;
        unsigned ha = bf16rne(av[cI]);
        float ra = av[cI] - __uint_as_float(ha << 16);
        unsigned la = bf16rne(ra);
        unsigned hb = bf16rne(bv[cI]);
        float rb = bv[cI] - __uint_as_float(hb << 16);
        unsigned lb = bf16rne(rb);
        int pc = (jj0 & 7) + 8 * ((pr >> 2) ^ (d & 7));
        *(unsigned*)(VhS + d * 72 + pc) = ha | (hb << 16);
        *(unsigned*)(VlS + d * 72 + pc) = la | (lb << 16);
      }
    }
    if (t < 192) {
      int rl2 = t >> 6, c2 = t & 63;
      if (c2 < 63) {
        int off = (rbase - (j0 >> 5) + rl2) * 63 + c2;
        csS[rl2 * 64 + c2] = make_float2(ch[off], che[off]);
      }
    }
    __syncthreads();

    f32x4 acc[4] = {};
#pragma unroll
    for (int c = 0; c < 2; ++c) {
#pragma unroll
      for (int T = 0; T < 4; ++T) {
        short8 bh8 = *(const short8*)(KhS + (16 * T + li) * 72 + 32 * c + 8 * q);
        short8 bl8 = *(const short8*)(KlS + (16 * T + li) * 72 + 32 * c + 8 * q);
        acc[T] = mfma16(qah[c], bh8, acc[T]);
        acc[T] = mfma16(qah[c], bl8, acc[T]);
        acc[T] = mfma16(qal[c], bh8, acc[T]);
      }
    }

#pragma unroll
    for (int T = 0; T < 4; ++T) {
      int jj = 16 * T + li;
#pragma unroll
      for (int r = 0; r < 4; ++r) {
        int il = 16 * w + 4 * q + r;
        int rl2 = (il >> 5) - (jj >> 5) + 1;
        int cc2 = (il & 31) - (jj & 31) + 31;
        float ey = csS[rl2 * 64 + cc2].y;
        float e0 = expf(acc[T][r] - m0f[r]);
        attn0[(size_t)(bh * NTOK + i0 + il) * NTOK + j0 + jj] = e0 * is0f[r];
        float at = e0 * ey * crf[r];
        float p = (at - thf[r] > 0.f) ? at : 0.f;
        denl[r] += p;
        PfS[il * 68 + jj] = p;
      }
    }
    // PV: A = P (same-wave private region), B = V^T frags
#pragma unroll
    for (int c = 0; c < 2; ++c) {
      const float* pp = PfS + (16 * w + li) * 68 + 32 * c + 8 * q;
      float pv8[8];
      *(float4*)(pv8) = *(const float4*)pp;
      *(float4*)(pv8 + 4) = *(const float4*)(pp + 4);
      short8 pah, pal;
      split8(pv8, pah, pal);
#pragma unroll
      for (int T = 0; T < 4; ++T) {
        int d = 16 * T + li;
        int sw = 8 * ((4 * c + q) ^ (li & 7));
        short8 vh8 = *(const short8*)(VhS + d * 72 + sw);
        short8 vl8 = *(const short8*)(VlS + d * 72 + sw);
        oacc[T] = mfma16(pah, vh8, oacc[T]);
        oacc[T] = mfma16(pah, vl8, oacc[T]);
        oacc[T] = mfma16(pal, vh8, oacc[T]);
      }
    }
    __syncthreads();
  }

  // scale by 1/(deno+1e-6), store o in (b,n,h,d)
#pragma unroll
  for (int r = 0; r < 4; ++r) {
    float dsum = denl[r];
#pragma unroll
    for (int off = 1; off < 16; off <<= 1) dsum += __shfl_xor(dsum, off);
    float pf = 1.f / (dsum + 1e-6f);
    int row = i0 + 16 * w + 4 * q + r;
#pragma unroll
    for (int T = 0; T < 4; ++T) {
      o[(((size_t)b * NTOK + row) * NH + h) * DH + 16 * T + li] = oacc[T][r] * pf;
    }
  }
}

// ---------------- Kernel 3: output GEMM (fp32) ----------------
__global__ __launch_bounds__(256) void k_out(const float* __restrict__ a,
                                             const float* __restrict__ w,
                                             const float* __restrict__ bias,
                                             float* __restrict__ c) {
  __shared__ float As[32][68];
  __shared__ float Bs[32][68];
  const int bx = blockIdx.x;
  const int by = blockIdx.y;
  const int t = threadIdx.x;
  const int tx = t & 15, ty = t >> 4;
  const int m0 = by * 64, n0 = bx * 64;
  float acc[4][4] = {};
  for (int k0 = 0; k0 < 512; k0 += 32) {
#pragma unroll
    for (int l = 0; l < 2; ++l) {
      int idx = t + l * 256;
      {
        int row = idx >> 3, c4 = idx & 7;
        float4 av = *(const float4*)(a + (size_t)(m0 + row) * 512 + k0 + c4 * 4);
        As[c4 * 4 + 0][row] = av.x; As[c4 * 4 + 1][row] = av.y;
        As[c4 * 4 + 2][row] = av.z; As[c4 * 4 + 3][row] = av.w;
      }
      {
        int row = idx >> 4, c4 = idx & 15;
        *(float4*)(&Bs[row][c4 * 4]) =
            *(const float4*)(w + (size_t)(k0 + row) * 512 + n0 + c4 * 4);
      }
    }
    __syncthreads();
#pragma unroll
    for (int kk = 0; kk < 32; ++kk) {
      float4 av = *(const float4*)(&As[kk][ty * 4]);
      float4 bv = *(const float4*)(&Bs[kk][tx * 4]);
      fma4x4(acc, av, bv);
    }
    __syncthreads();
  }
  float4 bv4 = *(const float4*)(bias + n0 + tx * 4);
#pragma unroll
  for (int u = 0; u < 4; ++u) {
    int m = m0 + ty * 4 + u;
    float4 val;
    val.x = acc[u][0] + bv4.x; val.y = acc[u][1] + bv4.y;
    val.z = acc[u][2] + bv4.z; val.w = acc[u][3] + bv4.w;
    *(float4*)(c + (size_t)m * 512 + n0 + tx * 4) = val;
  }
}

extern "C" void kernel_launch(void* const* d_in, const int* in_sizes, int n_in,
                              void* d_out, int out_size, void* d_ws, size_t ws_size,
                              hipStream_t stream) {
  const float* x    = (const float*)d_in[0];
  const float* prob = (const float*)d_in[1];
  const float* wqkv = (const float*)d_in[2];
  const float* t1   = (const float*)d_in[3];
  const float* t2   = (const float*)d_in[4];
  const float* sita = (const float*)d_in[5];
  const float* wt   = (const float*)d_in[6];
  const float* wout = (const float*)d_in[7];
  const float* bout = (const float*)d_in[8];
  const float* dis  = (const float*)d_in[10];

  float* out = (float*)d_out;
  float* attn0 = out + (size_t)BATCH * NTOK * 512;
  float* comb = (float*)d_ws;                            // 32768 floats
  float* combe = comb + 32768;                           // 32768 floats
  float* qkv = combe + 32768;                            // 3 * 2097152 floats
  float* o = qkv + (size_t)3 * BATCH * NH * NTOK * DH;   // 2097152 floats

  hipLaunchKernelGGL(k_comb, dim3(16), dim3(256), 0, stream, t1, t2, sita, dis, comb, combe);
  hipLaunchKernelGGL(k_qkv, dim3(24, 64), dim3(256), 0, stream, x, wqkv, qkv);
  hipLaunchKernelGGL(k_attn, dim3(16, 32), dim3(256), 0, stream,
                     qkv, prob, comb, combe, wt, attn0, o);
  hipLaunchKernelGGL(k_out, dim3(8, 64), dim3(256), 0, stream, o, wout, bout, out);
}